// Round 4
// baseline (312.666 us; speedup 1.0000x reference)
//
#include <hip/hip_runtime.h>
#include <math.h>

#define D_MODEL 1024
#define HEADS 16
#define HEAD_DIM 64
#define SEQ 2048
#define BATCH 2
#define KVT 64
#define QTILE 64

typedef __attribute__((ext_vector_type(8))) short bf16x8;
typedef __attribute__((ext_vector_type(4))) float f32x4;

__device__ __forceinline__ short f2bf(float f) {
    union { float f; unsigned u; } v; v.f = f;
    unsigned r = (v.u + 0x7FFFu + ((v.u >> 16) & 1u)) >> 16;
    return (short)r;
}

// ---------------------------------------------------------------------------
// f32 -> bf16 elementwise, 8 elems/thread
// ---------------------------------------------------------------------------
__global__ __launch_bounds__(256) void convert_bf16(
    const float* __restrict__ in, short* __restrict__ out, int n8) {
    int i = blockIdx.x * 256 + threadIdx.x;
    if (i >= n8) return;
    float4 a = ((const float4*)in)[2 * i];
    float4 b = ((const float4*)in)[2 * i + 1];
    short r[8] = {f2bf(a.x), f2bf(a.y), f2bf(a.z), f2bf(a.w),
                  f2bf(b.x), f2bf(b.y), f2bf(b.z), f2bf(b.w)};
    *(uint4*)(out + 8 * i) = *(uint4*)r;
}

// ---------------------------------------------------------------------------
// mask int -> float 0 / -inf
// ---------------------------------------------------------------------------
__global__ __launch_bounds__(256) void mask_to_float(
    const int* __restrict__ mask, float* __restrict__ mf, int n) {
    int i = blockIdx.x * 256 + threadIdx.x;
    if (i < n) mf[i] = mask[i] ? 0.f : -INFINITY;
}

// ---------------------------------------------------------------------------
// Transpose-convert weights: W [K=1024][N=1024] f32 -> Wt [N][K] bf16.
// z = 0,1,2 -> Wq,Wk,Wv into concatenated [3072][1024]; z=3 -> Wp.
// ---------------------------------------------------------------------------
__global__ __launch_bounds__(256) void wtrans(
    const float* __restrict__ Wq, const float* __restrict__ Wk,
    const float* __restrict__ Wv, const float* __restrict__ Wp,
    short* __restrict__ Wqkvt, short* __restrict__ Wpt) {
    __shared__ float t[32][33];
    const int z = blockIdx.z;
    const float* W = z == 0 ? Wq : z == 1 ? Wk : z == 2 ? Wv : Wp;
    short* dst = (z < 3) ? Wqkvt + (size_t)z * 1024 * 1024 : Wpt;
    const int n0 = blockIdx.x * 32, k0 = blockIdx.y * 32;
    const int tx = threadIdx.x & 31, ty = threadIdx.x >> 5;
#pragma unroll
    for (int j = 0; j < 4; ++j)
        t[ty + j * 8][tx] = W[(size_t)(k0 + ty + j * 8) * 1024 + n0 + tx];
    __syncthreads();
#pragma unroll
    for (int j = 0; j < 4; ++j) {
        const int n = ty + j * 8;
        dst[(size_t)(n0 + n) * 1024 + k0 + tx] = f2bf(t[tx][n]);
    }
}

// ---------------------------------------------------------------------------
// bf16 MFMA GEMM (m97 structure): C[M,N] = A[M,K] @ Bt[N,K]^T + bias
// 128x128 tile, BK=32, 4 waves (2x2 of 64x64).
// Staging via global_load_lds width=16: linear LDS dest, granule-XOR
// pre-swizzled global source (undone at fragment read).
// MODE 0: f32 out row-major [M,N], bias b0.
// MODE 1: QKV fused (N=3072): bf16 head-split [B,H,S,Dh] into o0/o1/o2.
// ---------------------------------------------------------------------------
template <int MODE>
__global__ __launch_bounds__(256) void mfma_gemm(
    const short* __restrict__ A, const short* __restrict__ Bt,
    const float* __restrict__ b0, const float* __restrict__ b1,
    const float* __restrict__ b2, float* __restrict__ outf,
    short* __restrict__ o0, short* __restrict__ o1, short* __restrict__ o2,
    int M, int N, int K) {
    __shared__ short As[128 * 32];  // [row][granule16B], holds src granule g^((r>>1)&3)
    __shared__ short Bs[128 * 32];

    const int tid = threadIdx.x;
    const int wave = tid >> 6, lane = tid & 63;
    const int l15 = lane & 15, lhi = lane >> 4;
    const int wm = wave >> 1, wn = wave & 1;
    const int bm0 = blockIdx.y * 128, bn0 = blockIdx.x * 128;

    f32x4 acc[4][4];
#pragma unroll
    for (int m = 0; m < 4; ++m)
#pragma unroll
        for (int n = 0; n < 4; ++n) acc[m][n] = (f32x4){0.f, 0.f, 0.f, 0.f};

    // per wave-issue p: granules o = (wave*2+p)*64 + lane; lane writes LDS
    // at (uniform base) + lane*16. Source granule gs = (o&3) ^ ((row>>1)&3).
    const int NT = K / 32;
    for (int kt = 0; kt < NT; ++kt) {
        const int k0 = kt * 32;
#pragma unroll
        for (int p = 0; p < 2; ++p) {
            const int o = (wave * 2 + p) * 64 + lane;
            const int r = o >> 2;
            const int gs = (o & 3) ^ ((r >> 1) & 3);
            const short* ga = A + (size_t)(bm0 + r) * K + k0 + gs * 8;
            const short* gb = Bt + (size_t)(bn0 + r) * K + k0 + gs * 8;
            __builtin_amdgcn_global_load_lds(
                (const __attribute__((address_space(1))) void*)ga,
                (__attribute__((address_space(3))) void*)(As + (size_t)(wave * 2 + p) * 512),
                16, 0, 0);
            __builtin_amdgcn_global_load_lds(
                (const __attribute__((address_space(1))) void*)gb,
                (__attribute__((address_space(3))) void*)(Bs + (size_t)(wave * 2 + p) * 512),
                16, 0, 0);
        }
        __syncthreads();
        bf16x8 af[4], bf[4];
        const int sg = (lhi ^ ((l15 >> 1) & 3)) * 16;
#pragma unroll
        for (int m = 0; m < 4; ++m)
            af[m] = *(const bf16x8*)((char*)As + (wm * 64 + m * 16 + l15) * 64 + sg);
#pragma unroll
        for (int n = 0; n < 4; ++n)
            bf[n] = *(const bf16x8*)((char*)Bs + (wn * 64 + n * 16 + l15) * 64 + sg);
        __builtin_amdgcn_s_setprio(1);
#pragma unroll
        for (int m = 0; m < 4; ++m)
#pragma unroll
            for (int n = 0; n < 4; ++n)
                acc[m][n] = __builtin_amdgcn_mfma_f32_16x16x32_bf16(af[m], bf[n], acc[m][n], 0, 0, 0);
        __builtin_amdgcn_s_setprio(0);
        __syncthreads();
    }

    // epilogue: row=(lane>>4)*4+rr, col=lane&15 within fragment
#pragma unroll
    for (int m = 0; m < 4; ++m) {
#pragma unroll
        for (int n = 0; n < 4; ++n) {
            const int col = bn0 + wn * 64 + n * 16 + l15;
#pragma unroll
            for (int rr = 0; rr < 4; ++rr) {
                const int row = bm0 + wm * 64 + m * 16 + lhi * 4 + rr;
                const float v = acc[m][n][rr];
                if (MODE == 0) {
                    outf[(size_t)row * N + col] = v + b0[col];
                } else {
                    const int which = col >> 10;
                    const int cc = col & 1023;
                    const int h = cc >> 6, dh = cc & 63;
                    const int b = row >> 11, s = row & (SEQ - 1);
                    const float bias = (which == 0 ? b0 : which == 1 ? b1 : b2)[cc];
                    short* dst = which == 0 ? o0 : which == 1 ? o1 : o2;
                    dst[(((size_t)(b * HEADS + h)) * SEQ + s) * HEAD_DIM + dh] = f2bf(v + bias);
                }
            }
        }
    }
}

// ---------------------------------------------------------------------------
// V [B,H,S,Dh] bf16 -> Vt [B,H,Dh,S] bf16  (64x64 LDS tiles)
// ---------------------------------------------------------------------------
__global__ __launch_bounds__(256) void transpose_v(
    const short* __restrict__ V, short* __restrict__ Vt) {
    __shared__ short t[64][66];
    const int bh = blockIdx.y, s0 = blockIdx.x * 64;
    const int tx = threadIdx.x, ty = threadIdx.y;
    const short* src = V + ((size_t)bh * SEQ + s0) * 64;
#pragma unroll
    for (int j = 0; j < 16; ++j) {
        const int sl = ty * 16 + j;
        t[sl][tx] = src[(size_t)sl * 64 + tx];
    }
    __syncthreads();
    short* dst = Vt + (size_t)bh * 64 * SEQ + s0;
#pragma unroll
    for (int j = 0; j < 16; ++j) {
        const int dh = ty * 16 + j;
        dst[(size_t)dh * SEQ + tx] = t[tx][dh];
    }
}

// ---------------------------------------------------------------------------
// Flash attention, bf16 MFMA, BARRIER-FREE:
// K and V fragments are 16B-contiguous in global and L2-resident (512 KB per
// (b,h)) -> read them directly, no LDS staging, no __syncthreads at all.
// Only the per-wave P redistribution goes through LDS (wave-local).
// XCD-aware block swizzle keeps all 32 q-tiles of one (b,h) on one XCD.
// ---------------------------------------------------------------------------
__global__ __launch_bounds__(256, 4) void flash_attn(
    const short* __restrict__ Q, const short* __restrict__ K,
    const short* __restrict__ Vt, const float* __restrict__ maskf,
    short* __restrict__ Y) {
    __shared__ unsigned char pb[4][16 * 128];  // per-wave P, swizzled

    const int tid = threadIdx.x;
    const int wave = tid >> 6;
    const int lane = tid & 63;
    const int l15 = lane & 15;
    const int lhi = lane >> 4;

    // XCD swizzle: grid=1024, 1024%8==0 -> XCD x gets blocks [x*128,(x+1)*128)
    const int nwg = gridDim.x;
    const int wg = blockIdx.x;
    const int swz = (wg & 7) * (nwg >> 3) + (wg >> 3);
    const int qt = swz & 31;
    const int bh = swz >> 5;
    const int b = bh >> 4;

    const int q0 = qt * QTILE + wave * 16;

    const short* Qp = Q + ((size_t)bh * SEQ + q0 + l15) * HEAD_DIM;
    bf16x8 qf[2];
    qf[0] = *(const bf16x8*)(Qp + 8 * lhi);
    qf[1] = *(const bf16x8*)(Qp + 8 * lhi + 32);

    const short* Kb = K + (size_t)bh * SEQ * HEAD_DIM;
    const short* Vb = Vt + (size_t)bh * HEAD_DIM * SEQ;
    const float* mb = maskf + b * SEQ;

    f32x4 accO[4];
    float mrow[4], lrow[4];
#pragma unroll
    for (int i = 0; i < 4; ++i) {
        accO[i] = (f32x4){0.f, 0.f, 0.f, 0.f};
        mrow[i] = -INFINITY;
        lrow[i] = 0.f;
    }

    for (int kv = 0; kv < SEQ / KVT; ++kv) {
        const int k0 = kv * KVT;
        float ma[4];
#pragma unroll
        for (int nt = 0; nt < 4; ++nt) ma[nt] = mb[k0 + l15 + 16 * nt];

        // ---- QK^T straight from global (L2): kf = K[k0+l15+16nt][32c+8lhi..]
        f32x4 accS[4];
#pragma unroll
        for (int nt = 0; nt < 4; ++nt) accS[nt] = (f32x4){0.f, 0.f, 0.f, 0.f};
#pragma unroll
        for (int c = 0; c < 2; ++c) {
            bf16x8 kf[4];
#pragma unroll
            for (int nt = 0; nt < 4; ++nt)
                kf[nt] = *(const bf16x8*)(Kb + (size_t)(k0 + l15 + 16 * nt) * HEAD_DIM +
                                          32 * c + 8 * lhi);
            __builtin_amdgcn_s_setprio(1);
#pragma unroll
            for (int nt = 0; nt < 4; ++nt)
                accS[nt] = __builtin_amdgcn_mfma_f32_16x16x32_bf16(qf[c], kf[nt], accS[nt], 0, 0, 0);
            __builtin_amdgcn_s_setprio(0);
        }

        // ---- scale + mask in place
#pragma unroll
        for (int nt = 0; nt < 4; ++nt)
#pragma unroll
            for (int r = 0; r < 4; ++r) accS[nt][r] = accS[nt][r] * 0.125f + ma[nt];

        // ---- online softmax per row (row = lhi*4+r, spread over 16 lanes)
#pragma unroll
        for (int r = 0; r < 4; ++r) {
            float tmax = fmaxf(fmaxf(accS[0][r], accS[1][r]), fmaxf(accS[2][r], accS[3][r]));
#pragma unroll
            for (int m = 1; m < 16; m <<= 1) tmax = fmaxf(tmax, __shfl_xor(tmax, m, 16));
            const float mn = fmaxf(mrow[r], tmax);
            const float alpha = (mn == -INFINITY) ? 1.f : __expf(mrow[r] - mn);
            float rs = 0.f;
#pragma unroll
            for (int nt = 0; nt < 4; ++nt) {
                const float pv = (mn == -INFINITY) ? 0.f : __expf(accS[nt][r] - mn);
                accS[nt][r] = pv;
                rs += pv;
            }
#pragma unroll
            for (int m = 1; m < 16; m <<= 1) rs += __shfl_xor(rs, m, 16);
            lrow[r] = lrow[r] * alpha + rs;
            mrow[r] = mn;
#pragma unroll
            for (int d = 0; d < 4; ++d) accO[d][r] *= alpha;
            const int qrow = lhi * 4 + r;
            unsigned char* pw = pb[wave] + qrow * 128;
            const int sw = (qrow & 7) << 4;
#pragma unroll
            for (int nt = 0; nt < 4; ++nt)
                *(short*)(pw + (((l15 + 16 * nt) * 2) ^ sw)) = f2bf(accS[nt][r]);
        }

        // ---- PV: P from wave-local LDS, V fragments straight from global
#pragma unroll
        for (int c = 0; c < 2; ++c) {
            bf16x8 pf = *(const bf16x8*)(pb[wave] + l15 * 128 +
                                         ((16 * lhi + 64 * c) ^ ((l15 & 7) << 4)));
            bf16x8 vf[4];
#pragma unroll
            for (int d = 0; d < 4; ++d)
                vf[d] = *(const bf16x8*)(Vb + (size_t)(l15 + 16 * d) * SEQ +
                                         k0 + 32 * c + 8 * lhi);
            __builtin_amdgcn_s_setprio(1);
#pragma unroll
            for (int d = 0; d < 4; ++d)
                accO[d] = __builtin_amdgcn_mfma_f32_16x16x32_bf16(pf, vf[d], accO[d], 0, 0, 0);
            __builtin_amdgcn_s_setprio(0);
        }
    }

    float inv[4];
#pragma unroll
    for (int r = 0; r < 4; ++r) inv[r] = (lrow[r] > 0.f) ? 1.f / lrow[r] : 0.f;
#pragma unroll
    for (int r = 0; r < 4; ++r) {
        const int qg = q0 + lhi * 4 + r;
        short* Yp = Y + ((size_t)b * SEQ + qg) * D_MODEL + (bh & 15) * HEAD_DIM;
#pragma unroll
        for (int d = 0; d < 4; ++d) Yp[l15 + 16 * d] = f2bf(accO[d][r] * inv[r]);
    }
}

// ---------------------------------------------------------------------------
extern "C" void kernel_launch(void* const* d_in, const int* in_sizes, int n_in,
                              void* d_out, int out_size, void* d_ws, size_t ws_size,
                              hipStream_t stream) {
    const float* x    = (const float*)d_in[0];
    const int*   mask = (const int*)  d_in[1];
    const float* Wq   = (const float*)d_in[2];
    const float* bq   = (const float*)d_in[3];
    const float* Wk   = (const float*)d_in[4];
    const float* bk   = (const float*)d_in[5];
    const float* Wv   = (const float*)d_in[6];
    const float* bv   = (const float*)d_in[7];
    const float* Wp   = (const float*)d_in[8];
    const float* bp   = (const float*)d_in[9];
    float* out = (float*)d_out;

    short* ws    = (short*)d_ws;
    short* xb    = ws;                          // 4M shorts
    short* Wqkvt = xb + ((size_t)4 << 20);      // 3M
    short* Wpt   = Wqkvt + ((size_t)3 << 20);   // 1M
    short* Qb    = Wpt + ((size_t)1 << 20);     // 4M
    short* Kb    = Qb + ((size_t)4 << 20);      // 4M
    short* Vb    = Kb + ((size_t)4 << 20);      // 4M
    short* Vtb   = Vb + ((size_t)4 << 20);      // 4M
    short* Yb    = Vtb + ((size_t)4 << 20);     // 4M
    float* maskf = (float*)Vb;  // Vb is dead after transpose_v

    const int M = BATCH * SEQ;  // 4096

    convert_bf16<<<dim3((M * D_MODEL / 8 + 255) / 256), 256, 0, stream>>>(x, xb, M * D_MODEL / 8);
    wtrans<<<dim3(32, 32, 4), 256, 0, stream>>>(Wq, Wk, Wv, Wp, Wqkvt, Wpt);

    mfma_gemm<1><<<dim3(3 * D_MODEL / 128, M / 128), 256, 0, stream>>>(
        xb, Wqkvt, bq, bk, bv, nullptr, Qb, Kb, Vb, M, 3 * D_MODEL, D_MODEL);

    transpose_v<<<dim3(SEQ / 64, BATCH * HEADS), dim3(64, 4), 0, stream>>>(Vb, Vtb);

    mask_to_float<<<dim3((BATCH * SEQ + 255) / 256), 256, 0, stream>>>(mask, maskf, BATCH * SEQ);

    flash_attn<<<dim3(BATCH * HEADS * (SEQ / QTILE)), 256, 0, stream>>>(Qb, Kb, Vtb, maskf, Yb);

    mfma_gemm<0><<<dim3(D_MODEL / 128, M / 128), 256, 0, stream>>>(
        Yb, Wpt, bp, bp, bp, out, nullptr, nullptr, nullptr, M, D_MODEL, D_MODEL);
}

// Round 5
// 180.019 us; speedup vs baseline: 1.7369x; 1.7369x over previous
//
#include <hip/hip_runtime.h>
#include <math.h>

#define D_MODEL 1024
#define HEADS 16
#define HEAD_DIM 64
#define SEQ 2048
#define BATCH 2
#define KVT 64
#define QTILE 64

typedef __attribute__((ext_vector_type(8))) short bf16x8;
typedef __attribute__((ext_vector_type(4))) float f32x4;

__device__ __forceinline__ short f2bf(float f) {
    union { float f; unsigned u; } v; v.f = f;
    unsigned r = (v.u + 0x7FFFu + ((v.u >> 16) & 1u)) >> 16;
    return (short)r;
}

// ---------------------------------------------------------------------------
// f32 -> bf16 elementwise, 8 elems/thread
// ---------------------------------------------------------------------------
__global__ __launch_bounds__(256) void convert_bf16(
    const float* __restrict__ in, short* __restrict__ out, int n8) {
    int i = blockIdx.x * 256 + threadIdx.x;
    if (i >= n8) return;
    float4 a = ((const float4*)in)[2 * i];
    float4 b = ((const float4*)in)[2 * i + 1];
    short r[8] = {f2bf(a.x), f2bf(a.y), f2bf(a.z), f2bf(a.w),
                  f2bf(b.x), f2bf(b.y), f2bf(b.z), f2bf(b.w)};
    *(uint4*)(out + 8 * i) = *(uint4*)r;
}

// ---------------------------------------------------------------------------
// mask int -> float 0 / -inf
// ---------------------------------------------------------------------------
__global__ __launch_bounds__(256) void mask_to_float(
    const int* __restrict__ mask, float* __restrict__ mf, int n) {
    int i = blockIdx.x * 256 + threadIdx.x;
    if (i < n) mf[i] = mask[i] ? 0.f : -INFINITY;
}

// ---------------------------------------------------------------------------
// Transpose-convert weights: W [K=1024][N=1024] f32 -> Wt [N][K] bf16.
// z = 0,1,2 -> Wq,Wk,Wv into concatenated [3072][1024]; z=3 -> Wp.
// ---------------------------------------------------------------------------
__global__ __launch_bounds__(256) void wtrans(
    const float* __restrict__ Wq, const float* __restrict__ Wk,
    const float* __restrict__ Wv, const float* __restrict__ Wp,
    short* __restrict__ Wqkvt, short* __restrict__ Wpt) {
    __shared__ float t[32][33];
    const int z = blockIdx.z;
    const float* W = z == 0 ? Wq : z == 1 ? Wk : z == 2 ? Wv : Wp;
    short* dst = (z < 3) ? Wqkvt + (size_t)z * 1024 * 1024 : Wpt;
    const int n0 = blockIdx.x * 32, k0 = blockIdx.y * 32;
    const int tx = threadIdx.x & 31, ty = threadIdx.x >> 5;
#pragma unroll
    for (int j = 0; j < 4; ++j)
        t[ty + j * 8][tx] = W[(size_t)(k0 + ty + j * 8) * 1024 + n0 + tx];
    __syncthreads();
#pragma unroll
    for (int j = 0; j < 4; ++j) {
        const int n = ty + j * 8;
        dst[(size_t)(n0 + n) * 1024 + k0 + tx] = f2bf(t[tx][n]);
    }
}

// ---------------------------------------------------------------------------
// bf16 MFMA GEMM: C[M,N] = A[M,K] @ Bt[N,K]^T + bias
// 128x128 tile, BK=32, 4 waves (2x2 of 64x64).
// global_load_lds width=16 staging, double-buffered, 1 barrier per K-step.
// MODE 0: f32 out row-major [M,N], bias b0.
// MODE 1: QKV fused (N=3072): bf16 head-split [B,H,S,Dh] into o0/o1/o2.
// ---------------------------------------------------------------------------
template <int MODE>
__global__ __launch_bounds__(256) void mfma_gemm(
    const short* __restrict__ A, const short* __restrict__ Bt,
    const float* __restrict__ b0, const float* __restrict__ b1,
    const float* __restrict__ b2, float* __restrict__ outf,
    short* __restrict__ o0, short* __restrict__ o1, short* __restrict__ o2,
    int M, int N, int K) {
    __shared__ short As[2 * 128 * 32];  // dbuf; [row][granule16B], src-swizzled
    __shared__ short Bs[2 * 128 * 32];

    const int tid = threadIdx.x;
    const int wave = tid >> 6, lane = tid & 63;
    const int l15 = lane & 15, lhi = lane >> 4;
    const int wm = wave >> 1, wn = wave & 1;
    const int bm0 = blockIdx.y * 128, bn0 = blockIdx.x * 128;

    f32x4 acc[4][4];
#pragma unroll
    for (int m = 0; m < 4; ++m)
#pragma unroll
        for (int n = 0; n < 4; ++n) acc[m][n] = (f32x4){0.f, 0.f, 0.f, 0.f};

    // granule o = (wave*2+p)*64 + lane; row r=o>>2; src granule (o&3)^((r>>1)&3)
#define STAGE_G(buf, kt_)                                                         \
    {                                                                             \
        const int k0 = (kt_) * 32;                                                \
        _Pragma("unroll") for (int p = 0; p < 2; ++p) {                           \
            const int o = (wave * 2 + p) * 64 + lane;                             \
            const int r = o >> 2;                                                 \
            const int gs = (o & 3) ^ ((r >> 1) & 3);                              \
            __builtin_amdgcn_global_load_lds(                                     \
                (const __attribute__((address_space(1))) void*)(                  \
                    A + (size_t)(bm0 + r) * K + k0 + gs * 8),                     \
                (__attribute__((address_space(3))) void*)(                        \
                    As + (size_t)(buf) * 4096 + (wave * 2 + p) * 512),            \
                16, 0, 0);                                                        \
            __builtin_amdgcn_global_load_lds(                                     \
                (const __attribute__((address_space(1))) void*)(                  \
                    Bt + (size_t)(bn0 + r) * K + k0 + gs * 8),                    \
                (__attribute__((address_space(3))) void*)(                        \
                    Bs + (size_t)(buf) * 4096 + (wave * 2 + p) * 512),            \
                16, 0, 0);                                                        \
        }                                                                         \
    }

    const int NT = K / 32;
    STAGE_G(0, 0);
    __syncthreads();
    for (int kt = 0; kt < NT; ++kt) {
        const int cur = kt & 1;
        if (kt + 1 < NT) STAGE_G((kt + 1) & 1, kt + 1);
        bf16x8 af[4], bf[4];
        const int sg = (lhi ^ ((l15 >> 1) & 3)) * 16;
#pragma unroll
        for (int m = 0; m < 4; ++m)
            af[m] = *(const bf16x8*)((char*)As + cur * 8192 +
                                     (wm * 64 + m * 16 + l15) * 64 + sg);
#pragma unroll
        for (int n = 0; n < 4; ++n)
            bf[n] = *(const bf16x8*)((char*)Bs + cur * 8192 +
                                     (wn * 64 + n * 16 + l15) * 64 + sg);
        __builtin_amdgcn_s_setprio(1);
#pragma unroll
        for (int m = 0; m < 4; ++m)
#pragma unroll
            for (int n = 0; n < 4; ++n)
                acc[m][n] = __builtin_amdgcn_mfma_f32_16x16x32_bf16(af[m], bf[n], acc[m][n], 0, 0, 0);
        __builtin_amdgcn_s_setprio(0);
        __syncthreads();
    }
#undef STAGE_G

    // epilogue: row=(lane>>4)*4+rr, col=lane&15 within fragment
#pragma unroll
    for (int m = 0; m < 4; ++m) {
#pragma unroll
        for (int n = 0; n < 4; ++n) {
            const int col = bn0 + wn * 64 + n * 16 + l15;
#pragma unroll
            for (int rr = 0; rr < 4; ++rr) {
                const int row = bm0 + wm * 64 + m * 16 + lhi * 4 + rr;
                const float v = acc[m][n][rr];
                if (MODE == 0) {
                    outf[(size_t)row * N + col] = v + b0[col];
                } else {
                    const int which = col >> 10;
                    const int cc = col & 1023;
                    const int h = cc >> 6, dh = cc & 63;
                    const int b = row >> 11, s = row & (SEQ - 1);
                    const float bias = (which == 0 ? b0 : which == 1 ? b1 : b2)[cc];
                    short* dst = which == 0 ? o0 : which == 1 ? o1 : o2;
                    dst[(((size_t)(b * HEADS + h)) * SEQ + s) * HEAD_DIM + dh] = f2bf(v + bias);
                }
            }
        }
    }
}

// ---------------------------------------------------------------------------
// V [B,H,S,Dh] bf16 -> Vt [B,H,Dh,S] bf16  (64x64 LDS tiles)
// ---------------------------------------------------------------------------
__global__ __launch_bounds__(256) void transpose_v(
    const short* __restrict__ V, short* __restrict__ Vt) {
    __shared__ short t[64][66];
    const int bh = blockIdx.y, s0 = blockIdx.x * 64;
    const int tx = threadIdx.x, ty = threadIdx.y;
    const short* src = V + ((size_t)bh * SEQ + s0) * 64;
#pragma unroll
    for (int j = 0; j < 16; ++j) {
        const int sl = ty * 16 + j;
        t[sl][tx] = src[(size_t)sl * 64 + tx];
    }
    __syncthreads();
    short* dst = Vt + (size_t)bh * 64 * SEQ + s0;
#pragma unroll
    for (int j = 0; j < 16; ++j) {
        const int dh = ty * 16 + j;
        dst[(size_t)dh * SEQ + tx] = t[tx][dh];
    }
}

// ---------------------------------------------------------------------------
// Flash attention, bf16 MFMA. LDS-staged K/V via global_load_lds (async,
// source row-XOR pre-swizzled, linear LDS dest), double-buffered, ONE barrier
// per KV tile. Per-wave P through LDS. XCD swizzle + setprio.
// ---------------------------------------------------------------------------
__global__ __launch_bounds__(256, 4) void flash_attn(
    const short* __restrict__ Q, const short* __restrict__ K,
    const short* __restrict__ Vt, const float* __restrict__ maskf,
    short* __restrict__ Y) {
    __shared__ unsigned char kt[2][KVT * 128];       // 16 KB
    __shared__ unsigned char vt[2][HEAD_DIM * 128];  // 16 KB
    __shared__ unsigned char pb[4][16 * 128];        // 8 KB

    const int tid = threadIdx.x;
    const int wave = tid >> 6;
    const int lane = tid & 63;
    const int l15 = lane & 15;
    const int lhi = lane >> 4;

    // XCD swizzle: grid=1024 (div by 8) -> XCD x gets 128 consecutive blocks
    const int nwg = gridDim.x;
    const int wg = blockIdx.x;
    const int swz = (wg & 7) * (nwg >> 3) + (wg >> 3);
    const int qt = swz & 31;
    const int bh = swz >> 5;
    const int b = bh >> 4;

    const int q0 = qt * QTILE + wave * 16;

    const short* Qp = Q + ((size_t)bh * SEQ + q0 + l15) * HEAD_DIM;
    bf16x8 qf[2];
    qf[0] = *(const bf16x8*)(Qp + 8 * lhi);
    qf[1] = *(const bf16x8*)(Qp + 8 * lhi + 32);

    const unsigned char* Kb8 = (const unsigned char*)(K + (size_t)bh * SEQ * HEAD_DIM);
    const unsigned char* Vb8 = (const unsigned char*)(Vt + (size_t)bh * HEAD_DIM * SEQ);
    const float* mb = maskf + b * SEQ;

    // stage tile kvi into buf: rows (key / dh) of 128B, granule o=(wave*2+p)*64+lane,
    // LDS linear at o*16, global source inner XOR'd by ((row&7)<<4)
#define STAGE(buf, kvi)                                                            \
    {                                                                              \
        const unsigned char* kbase = Kb8 + (size_t)(kvi) * KVT * 128;              \
        const unsigned char* vbase = Vb8 + (size_t)(kvi) * 128;                    \
        _Pragma("unroll") for (int p = 0; p < 2; ++p) {                            \
            const int o = (wave * 2 + p) * 64 + lane;                              \
            const int row = o >> 3;                                                \
            const int inner = (o & 7) * 16;                                        \
            const int src = inner ^ ((row & 7) << 4);                              \
            __builtin_amdgcn_global_load_lds(                                      \
                (const __attribute__((address_space(1))) void*)(                   \
                    kbase + row * 128 + src),                                      \
                (__attribute__((address_space(3))) void*)(                         \
                    &kt[buf][(wave * 2 + p) * 1024]),                              \
                16, 0, 0);                                                         \
            __builtin_amdgcn_global_load_lds(                                      \
                (const __attribute__((address_space(1))) void*)(                   \
                    vbase + (size_t)row * (SEQ * 2) + src),                        \
                (__attribute__((address_space(3))) void*)(                         \
                    &vt[buf][(wave * 2 + p) * 1024]),                              \
                16, 0, 0);                                                         \
        }                                                                          \
    }

    f32x4 accO[4];
    float mrow[4], lrow[4];
#pragma unroll
    for (int i = 0; i < 4; ++i) {
        accO[i] = (f32x4){0.f, 0.f, 0.f, 0.f};
        mrow[i] = -INFINITY;
        lrow[i] = 0.f;
    }

    STAGE(0, 0);
    __syncthreads();

    for (int kv = 0; kv < SEQ / KVT; ++kv) {
        const int cur = kv & 1;
        if (kv + 1 < SEQ / KVT) STAGE((kv + 1) & 1, kv + 1);

        const int k0 = kv * KVT;
        float ma[4];
#pragma unroll
        for (int nt = 0; nt < 4; ++nt) ma[nt] = mb[k0 + l15 + 16 * nt];

        // ---- QK^T from kt[cur]
        f32x4 accS[4];
#pragma unroll
        for (int nt = 0; nt < 4; ++nt) accS[nt] = (f32x4){0.f, 0.f, 0.f, 0.f};
#pragma unroll
        for (int c = 0; c < 2; ++c) {
            bf16x8 kf[4];
#pragma unroll
            for (int nt = 0; nt < 4; ++nt) {
                const int key = l15 + 16 * nt;
                kf[nt] = *(const bf16x8*)(kt[cur] + key * 128 +
                                          ((16 * lhi + 64 * c) ^ ((key & 7) << 4)));
            }
            __builtin_amdgcn_s_setprio(1);
#pragma unroll
            for (int nt = 0; nt < 4; ++nt)
                accS[nt] = __builtin_amdgcn_mfma_f32_16x16x32_bf16(qf[c], kf[nt], accS[nt], 0, 0, 0);
            __builtin_amdgcn_s_setprio(0);
        }

        // ---- scale + mask
#pragma unroll
        for (int nt = 0; nt < 4; ++nt)
#pragma unroll
            for (int r = 0; r < 4; ++r) accS[nt][r] = accS[nt][r] * 0.125f + ma[nt];

        // ---- online softmax (row = lhi*4+r across 16 lanes)
#pragma unroll
        for (int r = 0; r < 4; ++r) {
            float tmax = fmaxf(fmaxf(accS[0][r], accS[1][r]), fmaxf(accS[2][r], accS[3][r]));
#pragma unroll
            for (int m = 1; m < 16; m <<= 1) tmax = fmaxf(tmax, __shfl_xor(tmax, m, 16));
            const float mn = fmaxf(mrow[r], tmax);
            const float alpha = (mn == -INFINITY) ? 1.f : __expf(mrow[r] - mn);
            float rs = 0.f;
#pragma unroll
            for (int nt = 0; nt < 4; ++nt) {
                const float pv = (mn == -INFINITY) ? 0.f : __expf(accS[nt][r] - mn);
                accS[nt][r] = pv;
                rs += pv;
            }
#pragma unroll
            for (int m = 1; m < 16; m <<= 1) rs += __shfl_xor(rs, m, 16);
            lrow[r] = lrow[r] * alpha + rs;
            mrow[r] = mn;
#pragma unroll
            for (int d = 0; d < 4; ++d) accO[d][r] *= alpha;
            const int qrow = lhi * 4 + r;
            unsigned char* pw = pb[wave] + qrow * 128;
            const int sw = (qrow & 7) << 4;
#pragma unroll
            for (int nt = 0; nt < 4; ++nt)
                *(short*)(pw + (((l15 + 16 * nt) * 2) ^ sw)) = f2bf(accS[nt][r]);
        }

        // ---- PV from vt[cur]
#pragma unroll
        for (int c = 0; c < 2; ++c) {
            bf16x8 pf = *(const bf16x8*)(pb[wave] + l15 * 128 +
                                         ((16 * lhi + 64 * c) ^ ((l15 & 7) << 4)));
            bf16x8 vf[4];
#pragma unroll
            for (int d = 0; d < 4; ++d) {
                const int dh = l15 + 16 * d;
                vf[d] = *(const bf16x8*)(vt[cur] + dh * 128 +
                                         ((16 * lhi + 64 * c) ^ ((dh & 7) << 4)));
            }
            __builtin_amdgcn_s_setprio(1);
#pragma unroll
            for (int d = 0; d < 4; ++d)
                accO[d] = __builtin_amdgcn_mfma_f32_16x16x32_bf16(pf, vf[d], accO[d], 0, 0, 0);
            __builtin_amdgcn_s_setprio(0);
        }
        __syncthreads();
    }
#undef STAGE

    float inv[4];
#pragma unroll
    for (int r = 0; r < 4; ++r) inv[r] = (lrow[r] > 0.f) ? 1.f / lrow[r] : 0.f;
#pragma unroll
    for (int r = 0; r < 4; ++r) {
        const int qg = q0 + lhi * 4 + r;
        short* Yp = Y + ((size_t)b * SEQ + qg) * D_MODEL + (bh & 15) * HEAD_DIM;
#pragma unroll
        for (int d = 0; d < 4; ++d) Yp[l15 + 16 * d] = f2bf(accO[d][r] * inv[r]);
    }
}

// ---------------------------------------------------------------------------
extern "C" void kernel_launch(void* const* d_in, const int* in_sizes, int n_in,
                              void* d_out, int out_size, void* d_ws, size_t ws_size,
                              hipStream_t stream) {
    const float* x    = (const float*)d_in[0];
    const int*   mask = (const int*)  d_in[1];
    const float* Wq   = (const float*)d_in[2];
    const float* bq   = (const float*)d_in[3];
    const float* Wk   = (const float*)d_in[4];
    const float* bk   = (const float*)d_in[5];
    const float* Wv   = (const float*)d_in[6];
    const float* bv   = (const float*)d_in[7];
    const float* Wp   = (const float*)d_in[8];
    const float* bp   = (const float*)d_in[9];
    float* out = (float*)d_out;

    short* ws    = (short*)d_ws;
    short* xb    = ws;                          // 4M shorts
    short* Wqkvt = xb + ((size_t)4 << 20);      // 3M
    short* Wpt   = Wqkvt + ((size_t)3 << 20);   // 1M
    short* Qb    = Wpt + ((size_t)1 << 20);     // 4M
    short* Kb    = Qb + ((size_t)4 << 20);      // 4M
    short* Vb    = Kb + ((size_t)4 << 20);      // 4M
    short* Vtb   = Vb + ((size_t)4 << 20);      // 4M
    short* Yb    = Vtb + ((size_t)4 << 20);     // 4M
    float* maskf = (float*)Vb;  // Vb dead after transpose_v (stream-ordered)

    const int M = BATCH * SEQ;  // 4096

    convert_bf16<<<dim3((M * D_MODEL / 8 + 255) / 256), 256, 0, stream>>>(x, xb, M * D_MODEL / 8);
    wtrans<<<dim3(32, 32, 4), 256, 0, stream>>>(Wq, Wk, Wv, Wp, Wqkvt, Wpt);

    mfma_gemm<1><<<dim3(3 * D_MODEL / 128, M / 128), 256, 0, stream>>>(
        xb, Wqkvt, bq, bk, bv, nullptr, Qb, Kb, Vb, M, 3 * D_MODEL, D_MODEL);

    transpose_v<<<dim3(SEQ / 64, BATCH * HEADS), dim3(64, 4), 0, stream>>>(Vb, Vtb);

    mask_to_float<<<dim3((BATCH * SEQ + 255) / 256), 256, 0, stream>>>(mask, maskf, BATCH * SEQ);

    flash_attn<<<dim3(BATCH * HEADS * (SEQ / QTILE)), 256, 0, stream>>>(Qb, Kb, Vtb, maskf, Yb);

    mfma_gemm<0><<<dim3(D_MODEL / 128, M / 128), 256, 0, stream>>>(
        Yb, Wpt, bp, bp, bp, out, nullptr, nullptr, nullptr, M, D_MODEL, D_MODEL);
}

// Round 6
// 144.034 us; speedup vs baseline: 2.1708x; 1.2498x over previous
//
#include <hip/hip_runtime.h>
#include <math.h>

#define D_MODEL 1024
#define HEADS 16
#define HEAD_DIM 64
#define SEQ 2048
#define BATCH 2
#define KVT 64
#define QTILE 64

typedef __attribute__((ext_vector_type(8))) short bf16x8;
typedef __attribute__((ext_vector_type(4))) float f32x4;

__device__ __forceinline__ short f2bf(float f) {
    union { float f; unsigned u; } v; v.f = f;
    unsigned r = (v.u + 0x7FFFu + ((v.u >> 16) & 1u)) >> 16;
    return (short)r;
}

__device__ __forceinline__ unsigned cvt_pk_bf16(float lo, float hi) {
    unsigned r;
    asm("v_cvt_pk_bf16_f32 %0, %1, %2" : "=v"(r) : "v"(lo), "v"(hi));
    return r;
}

// ---------------------------------------------------------------------------
// f32 -> bf16 elementwise, 8 elems/thread
// ---------------------------------------------------------------------------
__global__ __launch_bounds__(256) void convert_bf16(
    const float* __restrict__ in, short* __restrict__ out, int n8) {
    int i = blockIdx.x * 256 + threadIdx.x;
    if (i >= n8) return;
    float4 a = ((const float4*)in)[2 * i];
    float4 b = ((const float4*)in)[2 * i + 1];
    short r[8] = {f2bf(a.x), f2bf(a.y), f2bf(a.z), f2bf(a.w),
                  f2bf(b.x), f2bf(b.y), f2bf(b.z), f2bf(b.w)};
    *(uint4*)(out + 8 * i) = *(uint4*)r;
}

// ---------------------------------------------------------------------------
// mask int -> float 0 / -inf
// ---------------------------------------------------------------------------
__global__ __launch_bounds__(256) void mask_to_float(
    const int* __restrict__ mask, float* __restrict__ mf, int n) {
    int i = blockIdx.x * 256 + threadIdx.x;
    if (i < n) mf[i] = mask[i] ? 0.f : -INFINITY;
}

// ---------------------------------------------------------------------------
// Transpose-convert weights: W [K=1024][N=1024] f32 -> Wt [N][K] bf16.
// z = 0,1,2 -> Wq,Wk,Wv into concatenated [3072][1024]; z=3 -> Wp.
// ---------------------------------------------------------------------------
__global__ __launch_bounds__(256) void wtrans(
    const float* __restrict__ Wq, const float* __restrict__ Wk,
    const float* __restrict__ Wv, const float* __restrict__ Wp,
    short* __restrict__ Wqkvt, short* __restrict__ Wpt) {
    __shared__ float t[32][33];
    const int z = blockIdx.z;
    const float* W = z == 0 ? Wq : z == 1 ? Wk : z == 2 ? Wv : Wp;
    short* dst = (z < 3) ? Wqkvt + (size_t)z * 1024 * 1024 : Wpt;
    const int n0 = blockIdx.x * 32, k0 = blockIdx.y * 32;
    const int tx = threadIdx.x & 31, ty = threadIdx.x >> 5;
#pragma unroll
    for (int j = 0; j < 4; ++j)
        t[ty + j * 8][tx] = W[(size_t)(k0 + ty + j * 8) * 1024 + n0 + tx];
    __syncthreads();
#pragma unroll
    for (int j = 0; j < 4; ++j) {
        const int n = ty + j * 8;
        dst[(size_t)(n0 + n) * 1024 + k0 + tx] = f2bf(t[tx][n]);
    }
}

// ---------------------------------------------------------------------------
// bf16 MFMA GEMM: C[M,N] = A[M,K] @ Bt[N,K]^T + bias
// 128x128 tile, BK=32, 4 waves (2x2 of 64x64).
// global_load_lds width=16 staging, double-buffered, 1 barrier per K-step.
// MODE 0: f32 out row-major [M,N], bias b0.
// MODE 1: QKV fused (N=3072): bf16 head-split [B,H,S,Dh] into o0/o1/o2.
// ---------------------------------------------------------------------------
template <int MODE>
__global__ __launch_bounds__(256) void mfma_gemm(
    const short* __restrict__ A, const short* __restrict__ Bt,
    const float* __restrict__ b0, const float* __restrict__ b1,
    const float* __restrict__ b2, float* __restrict__ outf,
    short* __restrict__ o0, short* __restrict__ o1, short* __restrict__ o2,
    int M, int N, int K) {
    __shared__ short As[2 * 128 * 32];  // dbuf; [row][granule16B], src-swizzled
    __shared__ short Bs[2 * 128 * 32];

    const int tid = threadIdx.x;
    const int wave = tid >> 6, lane = tid & 63;
    const int l15 = lane & 15, lhi = lane >> 4;
    const int wm = wave >> 1, wn = wave & 1;
    const int bm0 = blockIdx.y * 128, bn0 = blockIdx.x * 128;

    f32x4 acc[4][4];
#pragma unroll
    for (int m = 0; m < 4; ++m)
#pragma unroll
        for (int n = 0; n < 4; ++n) acc[m][n] = (f32x4){0.f, 0.f, 0.f, 0.f};

    // granule o = (wave*2+p)*64 + lane; row r=o>>2; src granule (o&3)^((r>>1)&3)
#define STAGE_G(buf, kt_)                                                         \
    {                                                                             \
        const int k0 = (kt_) * 32;                                                \
        _Pragma("unroll") for (int p = 0; p < 2; ++p) {                           \
            const int o = (wave * 2 + p) * 64 + lane;                             \
            const int r = o >> 2;                                                 \
            const int gs = (o & 3) ^ ((r >> 1) & 3);                              \
            __builtin_amdgcn_global_load_lds(                                     \
                (const __attribute__((address_space(1))) void*)(                  \
                    A + (size_t)(bm0 + r) * K + k0 + gs * 8),                     \
                (__attribute__((address_space(3))) void*)(                        \
                    As + (size_t)(buf) * 4096 + (wave * 2 + p) * 512),            \
                16, 0, 0);                                                        \
            __builtin_amdgcn_global_load_lds(                                     \
                (const __attribute__((address_space(1))) void*)(                  \
                    Bt + (size_t)(bn0 + r) * K + k0 + gs * 8),                    \
                (__attribute__((address_space(3))) void*)(                        \
                    Bs + (size_t)(buf) * 4096 + (wave * 2 + p) * 512),            \
                16, 0, 0);                                                        \
        }                                                                         \
    }

    const int NT = K / 32;
    STAGE_G(0, 0);
    __syncthreads();
    for (int kt = 0; kt < NT; ++kt) {
        const int cur = kt & 1;
        if (kt + 1 < NT) STAGE_G((kt + 1) & 1, kt + 1);
        bf16x8 af[4], bf[4];
        const int sg = (lhi ^ ((l15 >> 1) & 3)) * 16;
#pragma unroll
        for (int m = 0; m < 4; ++m)
            af[m] = *(const bf16x8*)((char*)As + cur * 8192 +
                                     (wm * 64 + m * 16 + l15) * 64 + sg);
#pragma unroll
        for (int n = 0; n < 4; ++n)
            bf[n] = *(const bf16x8*)((char*)Bs + cur * 8192 +
                                     (wn * 64 + n * 16 + l15) * 64 + sg);
        __builtin_amdgcn_s_setprio(1);
#pragma unroll
        for (int m = 0; m < 4; ++m)
#pragma unroll
            for (int n = 0; n < 4; ++n)
                acc[m][n] = __builtin_amdgcn_mfma_f32_16x16x32_bf16(af[m], bf[n], acc[m][n], 0, 0, 0);
        __builtin_amdgcn_s_setprio(0);
        __syncthreads();
    }
#undef STAGE_G

    // epilogue: row=(lane>>4)*4+rr, col=lane&15 within fragment
#pragma unroll
    for (int m = 0; m < 4; ++m) {
#pragma unroll
        for (int n = 0; n < 4; ++n) {
            const int col = bn0 + wn * 64 + n * 16 + l15;
#pragma unroll
            for (int rr = 0; rr < 4; ++rr) {
                const int row = bm0 + wm * 64 + m * 16 + lhi * 4 + rr;
                const float v = acc[m][n][rr];
                if (MODE == 0) {
                    outf[(size_t)row * N + col] = v + b0[col];
                } else {
                    const int which = col >> 10;
                    const int cc = col & 1023;
                    const int h = cc >> 6, dh = cc & 63;
                    const int b = row >> 11, s = row & (SEQ - 1);
                    const float bias = (which == 0 ? b0 : which == 1 ? b1 : b2)[cc];
                    short* dst = which == 0 ? o0 : which == 1 ? o1 : o2;
                    dst[(((size_t)(b * HEADS + h)) * SEQ + s) * HEAD_DIM + dh] = f2bf(v + bias);
                }
            }
        }
    }
}

// ---------------------------------------------------------------------------
// V [B,H,S,Dh] bf16 -> Vt [B,H,Dh,S] bf16  (64x64 LDS tiles)
// ---------------------------------------------------------------------------
__global__ __launch_bounds__(256) void transpose_v(
    const short* __restrict__ V, short* __restrict__ Vt) {
    __shared__ short t[64][66];
    const int bh = blockIdx.y, s0 = blockIdx.x * 64;
    const int tx = threadIdx.x, ty = threadIdx.y;
    const short* src = V + ((size_t)bh * SEQ + s0) * 64;
#pragma unroll
    for (int j = 0; j < 16; ++j) {
        const int sl = ty * 16 + j;
        t[sl][tx] = src[(size_t)sl * 64 + tx];
    }
    __syncthreads();
    short* dst = Vt + (size_t)bh * 64 * SEQ + s0;
#pragma unroll
    for (int j = 0; j < 16; ++j) {
        const int dh = ty * 16 + j;
        dst[(size_t)dh * SEQ + tx] = t[tx][dh];
    }
}

// ---------------------------------------------------------------------------
// Flash attention, bf16 MFMA, SWAPPED operands:
//   QK^T = mfma(K, Q)  -> S[key = 16nt+4lhi+r][q = l15]: one q-row per lane,
//   softmax reduce = 15 in-lane ops + 2 shfl_xor (vs 32 shfl before);
//   P pack = 8 cvt_pk_bf16 + 4 ds_write_b64 (vs 64 VALU + 16 ds_write_b16);
//   PV = mfma(V, P)    -> O[dh = 16d+4lhi+r][q = l15], alpha per-lane-uniform.
// Finite max floor (-30000) removes all -inf cndmask guards.
// Defer-max (T13, THR=8) skips the rescale when the row max is stable.
// K/V staged via async global_load_lds, double-buffered, 1 barrier/tile.
// ---------------------------------------------------------------------------
__global__ __launch_bounds__(256, 4) void flash_attn(
    const short* __restrict__ Q, const short* __restrict__ K,
    const short* __restrict__ Vt, const float* __restrict__ maskf,
    short* __restrict__ Y) {
    __shared__ unsigned char kt[2][KVT * 128];       // 16 KB
    __shared__ unsigned char vt[2][HEAD_DIM * 128];  // 16 KB
    __shared__ unsigned char pb[4][16 * 128];        // 8 KB

    const int tid = threadIdx.x;
    const int wave = tid >> 6;
    const int lane = tid & 63;
    const int l15 = lane & 15;
    const int lhi = lane >> 4;

    // XCD swizzle: grid=1024 (div by 8) -> XCD x gets 128 consecutive blocks
    const int nwg = gridDim.x;
    const int wg = blockIdx.x;
    const int swz = (wg & 7) * (nwg >> 3) + (wg >> 3);
    const int qt = swz & 31;
    const int bh = swz >> 5;
    const int b = bh >> 4;

    const int q0 = qt * QTILE + wave * 16;

    const short* Qp = Q + ((size_t)bh * SEQ + q0 + l15) * HEAD_DIM;
    bf16x8 qf[2];
    qf[0] = *(const bf16x8*)(Qp + 8 * lhi);
    qf[1] = *(const bf16x8*)(Qp + 8 * lhi + 32);

    const unsigned char* Kb8 = (const unsigned char*)(K + (size_t)bh * SEQ * HEAD_DIM);
    const unsigned char* Vb8 = (const unsigned char*)(Vt + (size_t)bh * HEAD_DIM * SEQ);
    const float* mb = maskf + b * SEQ;

#define STAGE(buf, kvi)                                                            \
    {                                                                              \
        const unsigned char* kbase = Kb8 + (size_t)(kvi) * KVT * 128;              \
        const unsigned char* vbase = Vb8 + (size_t)(kvi) * 128;                    \
        _Pragma("unroll") for (int p = 0; p < 2; ++p) {                            \
            const int o = (wave * 2 + p) * 64 + lane;                              \
            const int row = o >> 3;                                                \
            const int inner = (o & 7) * 16;                                        \
            const int src = inner ^ ((row & 7) << 4);                              \
            __builtin_amdgcn_global_load_lds(                                      \
                (const __attribute__((address_space(1))) void*)(                   \
                    kbase + row * 128 + src),                                      \
                (__attribute__((address_space(3))) void*)(                         \
                    &kt[buf][(wave * 2 + p) * 1024]),                              \
                16, 0, 0);                                                         \
            __builtin_amdgcn_global_load_lds(                                      \
                (const __attribute__((address_space(1))) void*)(                   \
                    vbase + (size_t)row * (SEQ * 2) + src),                        \
                (__attribute__((address_space(3))) void*)(                         \
                    &vt[buf][(wave * 2 + p) * 1024]),                              \
                16, 0, 0);                                                         \
        }                                                                          \
    }

    f32x4 accO[4];
    float mrow = -30000.f, lrow = 0.f;
#pragma unroll
    for (int i = 0; i < 4; ++i) accO[i] = (f32x4){0.f, 0.f, 0.f, 0.f};

    STAGE(0, 0);
    __syncthreads();

    for (int kv = 0; kv < SEQ / KVT; ++kv) {
        const int cur = kv & 1;
        if (kv + 1 < SEQ / KVT) STAGE((kv + 1) & 1, kv + 1);

        const int k0 = kv * KVT;

        // ---- QK^T (swapped): accS[nt][r] = S[key=k0+16nt+4lhi+r][q=q0+l15]
        f32x4 accS[4];
#pragma unroll
        for (int nt = 0; nt < 4; ++nt) accS[nt] = (f32x4){0.f, 0.f, 0.f, 0.f};
#pragma unroll
        for (int c = 0; c < 2; ++c) {
            bf16x8 kf[4];
#pragma unroll
            for (int nt = 0; nt < 4; ++nt) {
                const int key = l15 + 16 * nt;
                kf[nt] = *(const bf16x8*)(kt[cur] + key * 128 +
                                          ((16 * lhi + 64 * c) ^ ((key & 7) << 4)));
            }
            __builtin_amdgcn_s_setprio(1);
#pragma unroll
            for (int nt = 0; nt < 4; ++nt)
                accS[nt] = __builtin_amdgcn_mfma_f32_16x16x32_bf16(kf[nt], qf[c], accS[nt], 0, 0, 0);
            __builtin_amdgcn_s_setprio(0);
        }

        // ---- scale + mask (mask component r <-> key 16nt+4lhi+r)
#pragma unroll
        for (int nt = 0; nt < 4; ++nt) {
            const f32x4 ma = *(const f32x4*)(mb + k0 + 16 * nt + 4 * lhi);
#pragma unroll
            for (int r = 0; r < 4; ++r) accS[nt][r] = accS[nt][r] * 0.125f + ma[r];
        }

        // ---- per-lane row max (16 values) + cross-lhi reduce
        float smax = accS[0][0];
#pragma unroll
        for (int nt = 0; nt < 4; ++nt)
#pragma unroll
            for (int r = 0; r < 4; ++r) smax = fmaxf(smax, accS[nt][r]);
        smax = fmaxf(smax, __shfl_xor(smax, 16));
        smax = fmaxf(smax, __shfl_xor(smax, 32));

        // ---- defer-max: only rescale when the row max grew past THR=8
        if (!__all(smax <= mrow + 8.f)) {
            const float mn = fmaxf(mrow, smax);
            const float alpha = __expf(mrow - mn);
            lrow *= alpha;
#pragma unroll
            for (int d = 0; d < 4; ++d)
#pragma unroll
                for (int r = 0; r < 4; ++r) accO[d][r] *= alpha;
            mrow = mn;
        }

        // ---- p = exp(s - mrow), row sum
        float rs = 0.f;
#pragma unroll
        for (int nt = 0; nt < 4; ++nt)
#pragma unroll
            for (int r = 0; r < 4; ++r) {
                const float pv = __expf(accS[nt][r] - mrow);
                accS[nt][r] = pv;
                rs += pv;
            }
        rs += __shfl_xor(rs, 16);
        rs += __shfl_xor(rs, 32);
        lrow += rs;

        // ---- pack P pairs -> [q][key] LDS (keys 16nt+4lhi+0..3 contiguous)
#pragma unroll
        for (int nt = 0; nt < 4; ++nt) {
            uint2 w;
            w.x = cvt_pk_bf16(accS[nt][0], accS[nt][1]);
            w.y = cvt_pk_bf16(accS[nt][2], accS[nt][3]);
            *(uint2*)(pb[wave] + l15 * 128 +
                      ((32 * nt + 8 * lhi) ^ ((l15 & 7) << 4))) = w;
        }

        // ---- PV (swapped): accO[d] = O[dh=16d+4lhi+r][q=l15]
#pragma unroll
        for (int c = 0; c < 2; ++c) {
            bf16x8 pf = *(const bf16x8*)(pb[wave] + l15 * 128 +
                                         ((16 * lhi + 64 * c) ^ ((l15 & 7) << 4)));
            bf16x8 vf[4];
#pragma unroll
            for (int d = 0; d < 4; ++d) {
                const int dh = l15 + 16 * d;
                vf[d] = *(const bf16x8*)(vt[cur] + dh * 128 +
                                         ((16 * lhi + 64 * c) ^ ((dh & 7) << 4)));
            }
            __builtin_amdgcn_s_setprio(1);
#pragma unroll
            for (int d = 0; d < 4; ++d)
                accO[d] = __builtin_amdgcn_mfma_f32_16x16x32_bf16(vf[d], pf, accO[d], 0, 0, 0);
            __builtin_amdgcn_s_setprio(0);
        }
        __syncthreads();
    }
#undef STAGE

    // ---- epilogue: lane owns q = q0+l15, dh = 16d+4lhi+r; 8B packed stores
    const float inv = (lrow > 0.f) ? 1.f / lrow : 0.f;
    const int qg = q0 + l15;
    short* Yp = Y + ((size_t)b * SEQ + qg) * D_MODEL + (bh & 15) * HEAD_DIM;
#pragma unroll
    for (int d = 0; d < 4; ++d) {
        uint2 w;
        w.x = cvt_pk_bf16(accO[d][0] * inv, accO[d][1] * inv);
        w.y = cvt_pk_bf16(accO[d][2] * inv, accO[d][3] * inv);
        *(uint2*)(Yp + 16 * d + 4 * lhi) = w;
    }
}

// ---------------------------------------------------------------------------
extern "C" void kernel_launch(void* const* d_in, const int* in_sizes, int n_in,
                              void* d_out, int out_size, void* d_ws, size_t ws_size,
                              hipStream_t stream) {
    const float* x    = (const float*)d_in[0];
    const int*   mask = (const int*)  d_in[1];
    const float* Wq   = (const float*)d_in[2];
    const float* bq   = (const float*)d_in[3];
    const float* Wk   = (const float*)d_in[4];
    const float* bk   = (const float*)d_in[5];
    const float* Wv   = (const float*)d_in[6];
    const float* bv   = (const float*)d_in[7];
    const float* Wp   = (const float*)d_in[8];
    const float* bp   = (const float*)d_in[9];
    float* out = (float*)d_out;

    short* ws    = (short*)d_ws;
    short* xb    = ws;                          // 4M shorts
    short* Wqkvt = xb + ((size_t)4 << 20);      // 3M
    short* Wpt   = Wqkvt + ((size_t)3 << 20);   // 1M
    short* Qb    = Wpt + ((size_t)1 << 20);     // 4M
    short* Kb    = Qb + ((size_t)4 << 20);      // 4M
    short* Vb    = Kb + ((size_t)4 << 20);      // 4M
    short* Vtb   = Vb + ((size_t)4 << 20);      // 4M
    short* Yb    = Vtb + ((size_t)4 << 20);     // 4M
    float* maskf = (float*)Vb;  // Vb dead after transpose_v (stream-ordered)

    const int M = BATCH * SEQ;  // 4096

    convert_bf16<<<dim3((M * D_MODEL / 8 + 255) / 256), 256, 0, stream>>>(x, xb, M * D_MODEL / 8);
    wtrans<<<dim3(32, 32, 4), 256, 0, stream>>>(Wq, Wk, Wv, Wp, Wqkvt, Wpt);

    mfma_gemm<1><<<dim3(3 * D_MODEL / 128, M / 128), 256, 0, stream>>>(
        xb, Wqkvt, bq, bk, bv, nullptr, Qb, Kb, Vb, M, 3 * D_MODEL, D_MODEL);

    transpose_v<<<dim3(SEQ / 64, BATCH * HEADS), dim3(64, 4), 0, stream>>>(Vb, Vtb);

    mask_to_float<<<dim3((BATCH * SEQ + 255) / 256), 256, 0, stream>>>(mask, maskf, BATCH * SEQ);

    flash_attn<<<dim3(BATCH * HEADS * (SEQ / QTILE)), 256, 0, stream>>>(Qb, Kb, Vtb, maskf, Yb);

    mfma_gemm<0><<<dim3(D_MODEL / 128, M / 128), 256, 0, stream>>>(
        Yb, Wpt, bp, bp, bp, out, nullptr, nullptr, nullptr, M, D_MODEL, D_MODEL);
}

// Round 8
// 135.162 us; speedup vs baseline: 2.3133x; 1.0656x over previous
//
#include <hip/hip_runtime.h>
#include <math.h>

#define D_MODEL 1024
#define HEADS 16
#define HEAD_DIM 64
#define SEQ 2048
#define BATCH 2
#define KVT 64
#define QTILE 64
#define SCALE_Q 0.18033688f  // 0.125 * log2(e): folded into Q so softmax runs in log2 domain

typedef __attribute__((ext_vector_type(8))) short bf16x8;
typedef __attribute__((ext_vector_type(4))) float f32x4;

__device__ __forceinline__ short f2bf(float f) {
    union { float f; unsigned u; } v; v.f = f;
    unsigned r = (v.u + 0x7FFFu + ((v.u >> 16) & 1u)) >> 16;
    return (short)r;
}

__device__ __forceinline__ unsigned cvt_pk_bf16(float lo, float hi) {
    unsigned r;
    asm("v_cvt_pk_bf16_f32 %0, %1, %2" : "=v"(r) : "v"(lo), "v"(hi));
    return r;
}

__device__ __forceinline__ float fexp2(float x) {
    float r;
    asm("v_exp_f32 %0, %1" : "=v"(r) : "v"(x));
    return r;
}

// ---------------------------------------------------------------------------
// prep: merged  x->bf16 (blocks [0,2048))  |  weight transpose-convert
// (blocks [2048,6144))  |  mask->float (blocks [6144,6160))
// ---------------------------------------------------------------------------
__global__ __launch_bounds__(256) void prep(
    const float* __restrict__ x, const float* __restrict__ Wq,
    const float* __restrict__ Wk, const float* __restrict__ Wv,
    const float* __restrict__ Wp, const int* __restrict__ mask,
    short* __restrict__ xb, short* __restrict__ Wqkvt,
    short* __restrict__ Wpt, float* __restrict__ maskf) {
    __shared__ float t[32][33];
    const int bid = blockIdx.x;
    if (bid < 2048) {
        const int i = bid * 256 + threadIdx.x;
        float4 a = ((const float4*)x)[2 * i];
        float4 b = ((const float4*)x)[2 * i + 1];
        short r[8] = {f2bf(a.x), f2bf(a.y), f2bf(a.z), f2bf(a.w),
                      f2bf(b.x), f2bf(b.y), f2bf(b.z), f2bf(b.w)};
        *(uint4*)(xb + 8 * i) = *(uint4*)r;
    } else if (bid < 6144) {
        const int tt = bid - 2048;
        const int z = tt >> 10;
        const int rem = tt & 1023;
        const float* W = z == 0 ? Wq : z == 1 ? Wk : z == 2 ? Wv : Wp;
        short* dst = (z < 3) ? Wqkvt + (size_t)z * 1024 * 1024 : Wpt;
        const int n0 = (rem & 31) * 32, k0 = (rem >> 5) * 32;
        const int tx = threadIdx.x & 31, ty = threadIdx.x >> 5;
#pragma unroll
        for (int j = 0; j < 4; ++j)
            t[ty + j * 8][tx] = W[(size_t)(k0 + ty + j * 8) * 1024 + n0 + tx];
        __syncthreads();
#pragma unroll
        for (int j = 0; j < 4; ++j) {
            const int n = ty + j * 8;
            dst[(size_t)(n0 + n) * 1024 + k0 + tx] = f2bf(t[tx][n]);
        }
    } else {
        const int i = (bid - 6144) * 256 + threadIdx.x;
        maskf[i] = mask[i] ? 0.f : -INFINITY;
    }
}

// ---------------------------------------------------------------------------
// bf16 MFMA GEMM: C[M,N] = A[M,K] @ Bt[N,K]^T + bias
// 128x128 tile, BK=32, 4 waves; global_load_lds dbuf staging.
// MODE 0: f32 out row-major [M,N].
// MODE 1: QKV fused (N=3072): Q third scaled by SCALE_Q, head-split bf16;
//         K third head-split bf16; V third written TRANSPOSED [B,H,Dh,S]
//         via packed 8B stores (acc components are consecutive s).
// ---------------------------------------------------------------------------
template <int MODE>
__global__ __launch_bounds__(256) void mfma_gemm(
    const short* __restrict__ A, const short* __restrict__ Bt,
    const float* __restrict__ b0, const float* __restrict__ b1,
    const float* __restrict__ b2, float* __restrict__ outf,
    short* __restrict__ o0, short* __restrict__ o1, short* __restrict__ o2,
    int M, int N, int K) {
    __shared__ short As[2 * 128 * 32];
    __shared__ short Bs[2 * 128 * 32];

    const int tid = threadIdx.x;
    const int wave = tid >> 6, lane = tid & 63;
    const int l15 = lane & 15, lhi = lane >> 4;
    const int wm = wave >> 1, wn = wave & 1;
    const int bm0 = blockIdx.y * 128, bn0 = blockIdx.x * 128;

    f32x4 acc[4][4];
#pragma unroll
    for (int m = 0; m < 4; ++m)
#pragma unroll
        for (int n = 0; n < 4; ++n) acc[m][n] = (f32x4){0.f, 0.f, 0.f, 0.f};

#define STAGE_G(buf, kt_)                                                         \
    {                                                                             \
        const int k0 = (kt_) * 32;                                                \
        _Pragma("unroll") for (int p = 0; p < 2; ++p) {                           \
            const int o = (wave * 2 + p) * 64 + lane;                             \
            const int r = o >> 2;                                                 \
            const int gs = (o & 3) ^ ((r >> 1) & 3);                              \
            __builtin_amdgcn_global_load_lds(                                     \
                (const __attribute__((address_space(1))) void*)(                  \
                    A + (size_t)(bm0 + r) * K + k0 + gs * 8),                     \
                (__attribute__((address_space(3))) void*)(                        \
                    As + (size_t)(buf) * 4096 + (wave * 2 + p) * 512),            \
                16, 0, 0);                                                        \
            __builtin_amdgcn_global_load_lds(                                     \
                (const __attribute__((address_space(1))) void*)(                  \
                    Bt + (size_t)(bn0 + r) * K + k0 + gs * 8),                    \
                (__attribute__((address_space(3))) void*)(                        \
                    Bs + (size_t)(buf) * 4096 + (wave * 2 + p) * 512),            \
                16, 0, 0);                                                        \
        }                                                                         \
    }

    const int NT = K / 32;
    STAGE_G(0, 0);
    __syncthreads();
    for (int kt = 0; kt < NT; ++kt) {
        const int cur = kt & 1;
        if (kt + 1 < NT) STAGE_G((kt + 1) & 1, kt + 1);
        bf16x8 af[4], bf[4];
        const int sg = (lhi ^ ((l15 >> 1) & 3)) * 16;
#pragma unroll
        for (int m = 0; m < 4; ++m)
            af[m] = *(const bf16x8*)((char*)As + cur * 8192 +
                                     (wm * 64 + m * 16 + l15) * 64 + sg);
#pragma unroll
        for (int n = 0; n < 4; ++n)
            bf[n] = *(const bf16x8*)((char*)Bs + cur * 8192 +
                                     (wn * 64 + n * 16 + l15) * 64 + sg);
        __builtin_amdgcn_s_setprio(1);
#pragma unroll
        for (int m = 0; m < 4; ++m)
#pragma unroll
            for (int n = 0; n < 4; ++n)
                acc[m][n] = __builtin_amdgcn_mfma_f32_16x16x32_bf16(af[m], bf[n], acc[m][n], 0, 0, 0);
        __builtin_amdgcn_s_setprio(0);
        __syncthreads();
    }
#undef STAGE_G

    const int which = (MODE == 1) ? (bn0 >> 10) : 0;  // block-uniform third
#pragma unroll
    for (int m = 0; m < 4; ++m) {
#pragma unroll
        for (int n = 0; n < 4; ++n) {
            const int col = bn0 + wn * 64 + n * 16 + l15;
            if (MODE == 0) {
#pragma unroll
                for (int rr = 0; rr < 4; ++rr) {
                    const int row = bm0 + wm * 64 + m * 16 + lhi * 4 + rr;
                    outf[(size_t)row * N + col] = acc[m][n][rr] + b0[col];
                }
            } else {
                const int cc = col & 1023;
                const int h = cc >> 6, dh = cc & 63;
                const int row0 = bm0 + wm * 64 + m * 16 + lhi * 4;
                const int b = row0 >> 11, s0 = row0 & (SEQ - 1);
                if (which == 2) {
                    // V transposed [B,H,Dh,S]: rr axis = consecutive s -> 8B pack
                    const float bias = b2[cc];
                    uint2 w;
                    w.x = cvt_pk_bf16(acc[m][n][0] + bias, acc[m][n][1] + bias);
                    w.y = cvt_pk_bf16(acc[m][n][2] + bias, acc[m][n][3] + bias);
                    *(uint2*)(o2 + ((size_t)(b * HEADS + h) * HEAD_DIM + dh) * SEQ + s0) = w;
                } else {
                    const float bias = (which == 0 ? b0 : b1)[cc];
                    short* dst = which == 0 ? o0 : o1;
#pragma unroll
                    for (int rr = 0; rr < 4; ++rr) {
                        float v = acc[m][n][rr] + bias;
                        if (which == 0) v *= SCALE_Q;
                        dst[(((size_t)(b * HEADS + h)) * SEQ + s0 + rr) * HEAD_DIM + dh] = f2bf(v);
                    }
                }
            }
        }
    }
}

// ---------------------------------------------------------------------------
// Flash attention, swapped-operand bf16 MFMA, log2-domain softmax.
//  - Q pre-scaled by 0.125*log2e at projection; p = v_exp_f32(s - m) directly.
//  - P LDS: XOR (l15<<3) swizzle -> conflict-free b64 writes AND b64 reads.
//  - xor-32 reduce via __shfl_xor (round-6-proven; permlane asm in round 7
//    broke because "+v","+v" with identical inputs let the register
//    allocator coalesce both operands into ONE VGPR -> in-place half swap,
//    not a pairwise exchange).
//  - defer-max THR = 11.5 (log2 units ~ e^8).
// ---------------------------------------------------------------------------
__global__ __launch_bounds__(256, 4) void flash_attn(
    const short* __restrict__ Q, const short* __restrict__ K,
    const short* __restrict__ Vt, const float* __restrict__ maskf,
    short* __restrict__ Y) {
    __shared__ unsigned char kt[2][KVT * 128];       // 16 KB
    __shared__ unsigned char vt[2][HEAD_DIM * 128];  // 16 KB
    __shared__ unsigned char pb[4][16 * 128];        // 8 KB

    const int tid = threadIdx.x;
    const int wave = tid >> 6;
    const int lane = tid & 63;
    const int l15 = lane & 15;
    const int lhi = lane >> 4;

    const int nwg = gridDim.x;
    const int wg = blockIdx.x;
    const int swz = (wg & 7) * (nwg >> 3) + (wg >> 3);
    const int qt = swz & 31;
    const int bh = swz >> 5;
    const int b = bh >> 4;

    const int q0 = qt * QTILE + wave * 16;

    const short* Qp = Q + ((size_t)bh * SEQ + q0 + l15) * HEAD_DIM;
    bf16x8 qf[2];
    qf[0] = *(const bf16x8*)(Qp + 8 * lhi);
    qf[1] = *(const bf16x8*)(Qp + 8 * lhi + 32);

    const unsigned char* Kb8 = (const unsigned char*)(K + (size_t)bh * SEQ * HEAD_DIM);
    const unsigned char* Vb8 = (const unsigned char*)(Vt + (size_t)bh * HEAD_DIM * SEQ);
    const float* mb = maskf + b * SEQ;

#define STAGE(buf, kvi)                                                            \
    {                                                                              \
        const unsigned char* kbase = Kb8 + (size_t)(kvi) * KVT * 128;              \
        const unsigned char* vbase = Vb8 + (size_t)(kvi) * 128;                    \
        _Pragma("unroll") for (int p = 0; p < 2; ++p) {                            \
            const int o = (wave * 2 + p) * 64 + lane;                              \
            const int row = o >> 3;                                                \
            const int inner = (o & 7) * 16;                                        \
            const int src = inner ^ ((row & 7) << 4);                              \
            __builtin_amdgcn_global_load_lds(                                      \
                (const __attribute__((address_space(1))) void*)(                   \
                    kbase + row * 128 + src),                                      \
                (__attribute__((address_space(3))) void*)(                         \
                    &kt[buf][(wave * 2 + p) * 1024]),                              \
                16, 0, 0);                                                         \
            __builtin_amdgcn_global_load_lds(                                      \
                (const __attribute__((address_space(1))) void*)(                   \
                    vbase + (size_t)row * (SEQ * 2) + src),                        \
                (__attribute__((address_space(3))) void*)(                         \
                    &vt[buf][(wave * 2 + p) * 1024]),                              \
                16, 0, 0);                                                         \
        }                                                                          \
    }

    f32x4 accO[4];
    float mrow = -30000.f, lrow = 0.f;
#pragma unroll
    for (int i = 0; i < 4; ++i) accO[i] = (f32x4){0.f, 0.f, 0.f, 0.f};

    STAGE(0, 0);
    __syncthreads();

    for (int kv = 0; kv < SEQ / KVT; ++kv) {
        const int cur = kv & 1;
        if (kv + 1 < SEQ / KVT) STAGE((kv + 1) & 1, kv + 1);

        const int k0 = kv * KVT;

        // ---- QK^T (swapped): accS[nt][r] = S[key=k0+16nt+4lhi+r][q=q0+l15]
        f32x4 accS[4];
#pragma unroll
        for (int nt = 0; nt < 4; ++nt) accS[nt] = (f32x4){0.f, 0.f, 0.f, 0.f};
#pragma unroll
        for (int c = 0; c < 2; ++c) {
            bf16x8 kf[4];
#pragma unroll
            for (int nt = 0; nt < 4; ++nt) {
                const int key = l15 + 16 * nt;
                kf[nt] = *(const bf16x8*)(kt[cur] + key * 128 +
                                          ((16 * lhi + 64 * c) ^ ((key & 7) << 4)));
            }
            __builtin_amdgcn_s_setprio(1);
#pragma unroll
            for (int nt = 0; nt < 4; ++nt)
                accS[nt] = __builtin_amdgcn_mfma_f32_16x16x32_bf16(kf[nt], qf[c], accS[nt], 0, 0, 0);
            __builtin_amdgcn_s_setprio(0);
        }

        // ---- mask add (scores already log2-scaled; mask is 0/-inf)
#pragma unroll
        for (int nt = 0; nt < 4; ++nt) {
            const f32x4 ma = *(const f32x4*)(mb + k0 + 16 * nt + 4 * lhi);
#pragma unroll
            for (int r = 0; r < 4; ++r) accS[nt][r] += ma[r];
        }

        // ---- row max: in-lane tree + xor16 + xor32 shfl
        float t0 = fmaxf(fmaxf(accS[0][0], accS[0][1]), fmaxf(accS[0][2], accS[0][3]));
        float t1 = fmaxf(fmaxf(accS[1][0], accS[1][1]), fmaxf(accS[1][2], accS[1][3]));
        float t2 = fmaxf(fmaxf(accS[2][0], accS[2][1]), fmaxf(accS[2][2], accS[2][3]));
        float t3 = fmaxf(fmaxf(accS[3][0], accS[3][1]), fmaxf(accS[3][2], accS[3][3]));
        float smax = fmaxf(fmaxf(t0, t1), fmaxf(t2, t3));
        smax = fmaxf(smax, __shfl_xor(smax, 16));
        smax = fmaxf(smax, __shfl_xor(smax, 32));

        // ---- defer-max rescale (log2 THR = 11.5 ~ e^8)
        if (!__all(smax <= mrow + 11.5f)) {
            const float mn = fmaxf(mrow, smax);
            const float alpha = fexp2(mrow - mn);
            lrow *= alpha;
#pragma unroll
            for (int d = 0; d < 4; ++d)
#pragma unroll
                for (int r = 0; r < 4; ++r) accO[d][r] *= alpha;
            mrow = mn;
        }

        // ---- p = exp2(s - m), row sum
        float rs = 0.f;
#pragma unroll
        for (int nt = 0; nt < 4; ++nt)
#pragma unroll
            for (int r = 0; r < 4; ++r) {
                const float pv = fexp2(accS[nt][r] - mrow);
                accS[nt][r] = pv;
                rs += pv;
            }
        rs += __shfl_xor(rs, 16);
        rs += __shfl_xor(rs, 32);
        lrow += rs;

        // ---- pack P -> [q][key] LDS, XOR(l15<<3): conflict-free b64 writes
#pragma unroll
        for (int nt = 0; nt < 4; ++nt) {
            uint2 w;
            w.x = cvt_pk_bf16(accS[nt][0], accS[nt][1]);
            w.y = cvt_pk_bf16(accS[nt][2], accS[nt][3]);
            *(uint2*)(pb[wave] + l15 * 128 + ((32 * nt + 8 * lhi) ^ (l15 << 3))) = w;
        }

        // ---- PV (swapped): pf via two conflict-free b64 reads per half
#pragma unroll
        for (int c = 0; c < 2; ++c) {
            union { bf16x8 v; uint2 u[2]; } pfu;
            pfu.u[0] = *(const uint2*)(pb[wave] + l15 * 128 +
                                       ((16 * lhi + 64 * c) ^ (l15 << 3)));
            pfu.u[1] = *(const uint2*)(pb[wave] + l15 * 128 +
                                       ((16 * lhi + 64 * c + 8) ^ (l15 << 3)));
            const bf16x8 pf = pfu.v;
            bf16x8 vf[4];
#pragma unroll
            for (int d = 0; d < 4; ++d) {
                const int dh = l15 + 16 * d;
                vf[d] = *(const bf16x8*)(vt[cur] + dh * 128 +
                                         ((16 * lhi + 64 * c) ^ ((dh & 7) << 4)));
            }
            __builtin_amdgcn_s_setprio(1);
#pragma unroll
            for (int d = 0; d < 4; ++d)
                accO[d] = __builtin_amdgcn_mfma_f32_16x16x32_bf16(vf[d], pf, accO[d], 0, 0, 0);
            __builtin_amdgcn_s_setprio(0);
        }
        __syncthreads();
    }
#undef STAGE

    // ---- epilogue: lane owns q = q0+l15, dh = 16d+4lhi+r; 8B packed stores
    const float inv = (lrow > 0.f) ? 1.f / lrow : 0.f;
    const int qg = q0 + l15;
    short* Yp = Y + ((size_t)b * SEQ + qg) * D_MODEL + (bh & 15) * HEAD_DIM;
#pragma unroll
    for (int d = 0; d < 4; ++d) {
        uint2 w;
        w.x = cvt_pk_bf16(accO[d][0] * inv, accO[d][1] * inv);
        w.y = cvt_pk_bf16(accO[d][2] * inv, accO[d][3] * inv);
        *(uint2*)(Yp + 16 * d + 4 * lhi) = w;
    }
}

// ---------------------------------------------------------------------------
extern "C" void kernel_launch(void* const* d_in, const int* in_sizes, int n_in,
                              void* d_out, int out_size, void* d_ws, size_t ws_size,
                              hipStream_t stream) {
    const float* x    = (const float*)d_in[0];
    const int*   mask = (const int*)  d_in[1];
    const float* Wq   = (const float*)d_in[2];
    const float* bq   = (const float*)d_in[3];
    const float* Wk   = (const float*)d_in[4];
    const float* bk   = (const float*)d_in[5];
    const float* Wv   = (const float*)d_in[6];
    const float* bv   = (const float*)d_in[7];
    const float* Wp   = (const float*)d_in[8];
    const float* bp   = (const float*)d_in[9];
    float* out = (float*)d_out;

    short* ws    = (short*)d_ws;
    short* xb    = ws;                          // 4M shorts
    short* Wqkvt = xb + ((size_t)4 << 20);      // 3M
    short* Wpt   = Wqkvt + ((size_t)3 << 20);   // 1M
    short* Qb    = Wpt + ((size_t)1 << 20);     // 4M
    short* Kb    = Qb + ((size_t)4 << 20);      // 4M
    short* Vtb   = Kb + ((size_t)4 << 20);      // 4M
    short* Yb    = Vtb + ((size_t)4 << 20);     // 4M
    float* maskf = (float*)(Yb + ((size_t)4 << 20));  // 4096 floats

    const int M = BATCH * SEQ;  // 4096

    prep<<<dim3(6160), 256, 0, stream>>>(x, Wq, Wk, Wv, Wp, mask,
                                         xb, Wqkvt, Wpt, maskf);

    mfma_gemm<1><<<dim3(3 * D_MODEL / 128, M / 128), 256, 0, stream>>>(
        xb, Wqkvt, bq, bk, bv, nullptr, Qb, Kb, Vtb, M, 3 * D_MODEL, D_MODEL);

    flash_attn<<<dim3(BATCH * HEADS * (SEQ / QTILE)), 256, 0, stream>>>(Qb, Kb, Vtb, maskf, Yb);

    mfma_gemm<0><<<dim3(D_MODEL / 128, M / 128), 256, 0, stream>>>(
        Yb, Wpt, bp, bp, bp, out, nullptr, nullptr, nullptr, M, D_MODEL, D_MODEL);
}